// Round 9
// baseline (162.596 us; speedup 1.0000x reference)
//
#include <hip/hip_runtime.h>
#include <hip/hip_bf16.h>

#define S_LEN 2048
#define D_DIM 64
#define BH 64
#define NWARP 4
#define QW 32                  // q rows per warp
#define QBLK (NWARP * QW)      // 128
#define KVBLK 64
#define NKT (S_LEN / KVBLK)    // 32
#define NWG (BH * S_LEN / QBLK)  // 1024
#define TILE_ELEMS (KVBLK * D_DIM)          // 4096 bf16 = 8KB
#define TILE_BYTES (TILE_ELEMS * 2)

typedef __bf16 bf16_t;
typedef bf16_t bf16x8 __attribute__((ext_vector_type(8)));
typedef float f32x4 __attribute__((ext_vector_type(4)));
typedef float f32x16 __attribute__((ext_vector_type(16)));

typedef const __attribute__((address_space(1))) void gvoid_t;
typedef __attribute__((address_space(3))) void lvoid_t;

// element-index swizzle for a 64-col bf16 tile (rows are 128B):
// byte ^= ((row&7)<<4)  ==  col ^= ((row&7)<<3)
__device__ __forceinline__ int swz64(int row, int col) {
  return (row << 6) + (col ^ ((row & 7) << 3));
}

union W4 { unsigned u[4]; bf16x8 v; };
union PK { bf16_t h[2]; unsigned u; };

// ---------------------------------------------------------------------------
// Pre-pass: K,V fp32 -> bf16 tiles in d_ws, stored as the exact swizzled LDS
// image (V transposed [d][pi(k)]), so the main kernel can DMA them linearly.
// ---------------------------------------------------------------------------
__global__ __launch_bounds__(256)
void preconv(const float* __restrict__ K, const float* __restrict__ V,
             bf16_t* __restrict__ Kws, bf16_t* __restrict__ Vws) {
  const int tile = blockIdx.x;            // bh*NKT + kt
  const int bh = tile >> 5, kt = tile & 31;
  const size_t base = (size_t)bh * S_LEN * D_DIM + (size_t)kt * KVBLK * D_DIM;
  const int tid = threadIdx.x;
  bf16_t* ko = Kws + (size_t)tile * TILE_ELEMS;
  bf16_t* vo = Vws + (size_t)tile * TILE_ELEMS;

  // K tile [64][64] fp32 -> bf16 swizzled
  const int krow = tid >> 2, kcb = tid & 3;
  const float* ks = K + base + (size_t)krow * D_DIM + kcb * 16;
  f32x4 kr[4];
#pragma unroll
  for (int i = 0; i < 4; ++i) kr[i] = *(const f32x4*)(ks + i * 4);
#pragma unroll
  for (int half = 0; half < 2; ++half) {
    bf16x8 f;
#pragma unroll
    for (int j = 0; j < 4; ++j) {
      f[j]     = (bf16_t)kr[half * 2][j];
      f[4 + j] = (bf16_t)kr[half * 2 + 1][j];
    }
    *(bf16x8*)&ko[swz64(krow, kcb * 16 + half * 8)] = f;
  }

  // V^T tile [d][pi(k)] packed pairs, swizzled
  const int vkp = tid & 31, vdb = tid >> 5;
  const int vk0 = vkp * 2;
  const int vcol = (((vk0 >> 2) ^ (vk0 >> 3)) & 1) ? (vk0 ^ 12) : vk0;
  const float* vs = V + base + (size_t)vk0 * D_DIM + vdb * 8;
  f32x4 vr[4];
  vr[0] = *(const f32x4*)vs;           vr[1] = *(const f32x4*)(vs + 4);
  vr[2] = *(const f32x4*)(vs + D_DIM); vr[3] = *(const f32x4*)(vs + D_DIM + 4);
#pragma unroll
  for (int j = 0; j < 8; ++j) {
    PK p;
    p.h[0] = (bf16_t)((j < 4) ? vr[0][j] : vr[1][j - 4]);
    p.h[1] = (bf16_t)((j < 4) ? vr[2][j] : vr[3][j - 4]);
    *(unsigned*)&vo[swz64(vdb * 8 + j, vcol)] = p.u;
  }
}

// ---------------------------------------------------------------------------
// Main kernel: DMA-staged flash attention with T15 half-tile pipeline:
// epoch t = [barrier | issue(t+1) | qk_h0(t) | finish_h1(t-1) | qk_h1(t) |
//            finish_h0(t) | vmcnt(0)] -- finish VALU overlaps qk MFMA in-wave.
// K x2 buffers, V x3 buffers (40 KB -> 4 blocks/CU). No-max softmax.
// ---------------------------------------------------------------------------
__global__ __launch_bounds__(256, 4)
void sdpa_fwd_ws(const float* __restrict__ Q, const bf16_t* __restrict__ Kws,
                 const bf16_t* __restrict__ Vws, float* __restrict__ O) {
  __shared__ bf16_t Klds[2][TILE_ELEMS];
  __shared__ bf16_t Vlds[3][TILE_ELEMS];

  // XCD-aware bijective swizzle (1024 = 8*128)
  const int bid = blockIdx.x;
  const int lb  = (bid & 7) * (NWG / 8) + (bid >> 3);
  const int bx  = lb & 15;
  const int bh  = lb >> 4;

  const int tid  = threadIdx.x;
  const int wave = tid >> 6;
  const int lane = tid & 63;
  const int lq   = lane & 31;
  const int h    = lane >> 5;

  const size_t base = (size_t)bh * S_LEN * D_DIM;
  const int q0 = bx * QBLK + wave * QW;
  const float qscale = 0.125f * 1.44269504089f;  // 1/sqrt(64) * log2(e)

  // Q B-operand fragments (log2-scaled): lane holds Q[q0+lq][c*16 + h*8 + j]
  bf16x8 qf[4];
  {
    const float* qp = Q + base + (size_t)(q0 + lq) * D_DIM + h * 8;
#pragma unroll
    for (int c = 0; c < 4; ++c) {
      f32x4 a = *(const f32x4*)(qp + c * 16);
      f32x4 b = *(const f32x4*)(qp + c * 16 + 4);
      bf16x8 f;
#pragma unroll
      for (int j = 0; j < 4; ++j) {
        f[j]     = (bf16_t)(a[j] * qscale);
        f[4 + j] = (bf16_t)(b[j] * qscale);
      }
      qf[c] = f;
    }
  }

  // DMA source (per-lane) and LDS dest (wave-uniform) bases
  const char* kg = (const char*)(Kws + (size_t)(bh * NKT) * TILE_ELEMS)
                   + wave * 2048 + lane * 16;
  const char* vg = (const char*)(Vws + (size_t)(bh * NKT) * TILE_ELEMS)
                   + wave * 2048 + lane * 16;

  auto issueK = [&](int kt, int buf) {
    const char* src = kg + (size_t)kt * TILE_BYTES;
    char* dst = (char*)&Klds[buf][0] + wave * 2048;
    __builtin_amdgcn_global_load_lds((gvoid_t*)src,          (lvoid_t*)dst,          16, 0, 0);
    __builtin_amdgcn_global_load_lds((gvoid_t*)(src + 1024), (lvoid_t*)(dst + 1024), 16, 0, 0);
  };
  auto issueV = [&](int kt, int buf) {
    const char* src = vg + (size_t)kt * TILE_BYTES;
    char* dst = (char*)&Vlds[0][0] + buf * TILE_BYTES + wave * 2048;
    __builtin_amdgcn_global_load_lds((gvoid_t*)src,          (lvoid_t*)dst,          16, 0, 0);
    __builtin_amdgcn_global_load_lds((gvoid_t*)(src + 1024), (lvoid_t*)(dst + 1024), 16, 0, 0);
  };

  f32x16 acc0 = {}, acc1 = {};   // O^T: col q=lq, rows d=(r&3)+8*(r>>2)+4h (+32 acc1)
  float lpart = 0.f;             // lane-local l partial; cross-half shfl at end

  // half-tile QK: role 0 -> K rows lq (k 0..31), role 1 -> rows 32+lq (k 32..63)
  auto qkh = [&](const bf16_t* Kb, int role) {
    f32x16 s = {};
    __builtin_amdgcn_s_setprio(1);
#pragma unroll
    for (int c = 0; c < 4; ++c) {
      bf16x8 kf = *(const bf16x8*)&Kb[swz64(role * 32 + lq, c * 16 + h * 8)];
      s = __builtin_amdgcn_mfma_f32_32x32x16_bf16(kf, qf[c], s, 0, 0, 0);
    }
    __builtin_amdgcn_s_setprio(0);
    return s;
  };

  // half-tile finish: exp -> lpart -> pack -> PV (kc = role*2 + {0,1})
  auto finh = [&](const bf16_t* Vb, int role, f32x16 s) {
#pragma unroll
    for (int r = 0; r < 16; ++r) s[r] = __builtin_amdgcn_exp2f(s[r]);
    float a0 = (s[0] + s[1]) + (s[2] + s[3]);
    float a1 = (s[4] + s[5]) + (s[6] + s[7]);
    float a2 = (s[8] + s[9]) + (s[10] + s[11]);
    float a3 = (s[12] + s[13]) + (s[14] + s[15]);
    lpart += (a0 + a1) + (a2 + a3);
    W4 w0, w1;
#pragma unroll
    for (int i = 0; i < 4; ++i) {
      PK a, b;
      a.h[0] = (bf16_t)s[2 * i];     a.h[1] = (bf16_t)s[2 * i + 1];
      b.h[0] = (bf16_t)s[8 + 2 * i]; b.h[1] = (bf16_t)s[8 + 2 * i + 1];
      w0.u[i] = a.u; w1.u[i] = b.u;
    }
    __builtin_amdgcn_s_setprio(1);
#pragma unroll
    for (int j = 0; j < 2; ++j) {
      const int kc = role * 2 + j;
      bf16x8 vf0 = *(const bf16x8*)&Vb[swz64(lq,      kc * 16 + h * 8)];
      bf16x8 vf1 = *(const bf16x8*)&Vb[swz64(32 + lq, kc * 16 + h * 8)];
      bf16x8 pf = j ? w1.v : w0.v;
      acc0 = __builtin_amdgcn_mfma_f32_32x32x16_bf16(vf0, pf, acc0, 0, 0, 0);
      acc1 = __builtin_amdgcn_mfma_f32_32x32x16_bf16(vf1, pf, acc1, 0, 0, 0);
    }
    __builtin_amdgcn_s_setprio(0);
  };

  f32x16 stA, stB, stP;

  // ---- prologue: tile 0
  issueK(0, 0); issueV(0, 0);
  asm volatile("s_waitcnt vmcnt(0)" ::: "memory");
  __builtin_amdgcn_s_barrier();
  __builtin_amdgcn_sched_barrier(0);
  issueK(1, 1); issueV(1, 1);
  stA = qkh(Klds[0], 0);
  stB = qkh(Klds[0], 1);
  finh(&Vlds[0][0], 0, stA);
  stP = stB;
  asm volatile("s_waitcnt vmcnt(0)" ::: "memory");

  int vbp = 0, vbc = 1, vbn = 2;   // V buffers for t-1, t, t+1

#pragma unroll 1
  for (int t = 1; t < NKT; ++t) {
    __builtin_amdgcn_s_barrier();            // tile t fully landed (all waves)
    __builtin_amdgcn_sched_barrier(0);
    if (t + 1 < NKT) { issueK(t + 1, (t + 1) & 1); issueV(t + 1, vbn); }

    const bf16_t* Kb = Klds[t & 1];
    const bf16_t* Vp = &Vlds[0][0] + vbp * TILE_ELEMS;
    const bf16_t* Vc = &Vlds[0][0] + vbc * TILE_ELEMS;

    stA = qkh(Kb, 0);        // MFMA: overlaps with ...
    finh(Vp, 1, stP);        // ... VALU finish of tile t-1 hi-half
    stB = qkh(Kb, 1);
    finh(Vc, 0, stA);        // finish tile t lo-half
    stP = stB;               // hi-half deferred to next epoch

    asm volatile("s_waitcnt vmcnt(0)" ::: "memory");  // t+1 landed (mine)

    int tmp = vbp; vbp = vbc; vbc = vbn; vbn = tmp;
  }
  // final deferred hi-half of tile NKT-1
  finh(&Vlds[0][0] + vbp * TILE_ELEMS, 1, stP);

  // ---- epilogue: O[q][d] = O^T / l
  float l = lpart + __shfl_xor(lpart, 32, 64);
  float invl = 1.0f / l;
  float* op = O + base + (size_t)(q0 + lq) * D_DIM;
#pragma unroll
  for (int r = 0; r < 16; ++r) {
    int d = (r & 3) + 8 * (r >> 2) + 4 * h;
    op[d]      = acc0[r] * invl;
    op[32 + d] = acc1[r] * invl;
  }
}

// ---------------------------------------------------------------------------
// Fallback (known-good round-4 kernel, no workspace) if ws_size too small.
// ---------------------------------------------------------------------------
__global__ __launch_bounds__(256, 2)
void sdpa_fwd_fb(const float* __restrict__ Q, const float* __restrict__ K,
                 const float* __restrict__ V, float* __restrict__ O) {
  __shared__ bf16_t Klds[2][KVBLK * D_DIM];
  __shared__ bf16_t VTlds[2][D_DIM * KVBLK];

  const int bid = blockIdx.x;
  const int lb  = (bid & 7) * (NWG / 8) + (bid >> 3);
  const int bx  = lb & 15;
  const int bh  = lb >> 4;

  const int tid  = threadIdx.x;
  const int wave = tid >> 6;
  const int lane = tid & 63;
  const int lq   = lane & 31;
  const int h    = lane >> 5;

  const size_t base = (size_t)bh * S_LEN * D_DIM;
  const int q0 = bx * QBLK + wave * QW;
  const float qscale = 0.125f * 1.44269504089f;

  bf16x8 qf[4];
  {
    const float* qp = Q + base + (size_t)(q0 + lq) * D_DIM + h * 8;
#pragma unroll
    for (int c = 0; c < 4; ++c) {
      f32x4 a = *(const f32x4*)(qp + c * 16);
      f32x4 b = *(const f32x4*)(qp + c * 16 + 4);
      bf16x8 f;
#pragma unroll
      for (int j = 0; j < 4; ++j) {
        f[j]     = (bf16_t)(a[j] * qscale);
        f[4 + j] = (bf16_t)(b[j] * qscale);
      }
      qf[c] = f;
    }
  }

  const int krow = tid >> 2, kcb = tid & 3;
  const int vkp = tid & 31, vdb = tid >> 5;
  const int vk0 = vkp * 2;
  const int vcol = (((vk0 >> 2) ^ (vk0 >> 3)) & 1) ? (vk0 ^ 12) : vk0;

  f32x4 kr[4], vr[4];

  auto issue = [&](int kt) {
    const float* ks = K + base + (size_t)(kt * KVBLK + krow) * D_DIM + kcb * 16;
#pragma unroll
    for (int i = 0; i < 4; ++i) kr[i] = *(const f32x4*)(ks + i * 4);
    const float* vs = V + base + (size_t)(kt * KVBLK + vk0) * D_DIM + vdb * 8;
    vr[0] = *(const f32x4*)vs;           vr[1] = *(const f32x4*)(vs + 4);
    vr[2] = *(const f32x4*)(vs + D_DIM); vr[3] = *(const f32x4*)(vs + D_DIM + 4);
  };

  auto stage = [&](int buf) {
#pragma unroll
    for (int half = 0; half < 2; ++half) {
      bf16x8 f;
#pragma unroll
      for (int j = 0; j < 4; ++j) {
        f[j]     = (bf16_t)kr[half * 2][j];
        f[4 + j] = (bf16_t)kr[half * 2 + 1][j];
      }
      *(bf16x8*)&Klds[buf][swz64(krow, kcb * 16 + half * 8)] = f;
    }
#pragma unroll
    for (int j = 0; j < 8; ++j) {
      PK p;
      p.h[0] = (bf16_t)((j < 4) ? vr[0][j] : vr[1][j - 4]);
      p.h[1] = (bf16_t)((j < 4) ? vr[2][j] : vr[3][j - 4]);
      *(unsigned*)&VTlds[buf][swz64(vdb * 8 + j, vcol)] = p.u;
    }
  };

  f32x16 acc0 = {}, acc1 = {};
  float m = -1e30f, l = 0.f;

  issue(0);
  stage(0);
  __syncthreads();

  for (int kt = 0; kt < NKT; ++kt) {
    const int cur = kt & 1;
    if (kt + 1 < NKT) issue(kt + 1);

    const bf16_t* Kb = Klds[cur];
    const bf16_t* Vb = VTlds[cur];

    f32x16 st0 = {}, st1 = {};
    __builtin_amdgcn_s_setprio(1);
#pragma unroll
    for (int c = 0; c < 4; ++c) {
      bf16x8 kf0 = *(const bf16x8*)&Kb[swz64(lq, c * 16 + h * 8)];
      bf16x8 kf1 = *(const bf16x8*)&Kb[swz64(32 + lq, c * 16 + h * 8)];
      st0 = __builtin_amdgcn_mfma_f32_32x32x16_bf16(kf0, qf[c], st0, 0, 0, 0);
      st1 = __builtin_amdgcn_mfma_f32_32x32x16_bf16(kf1, qf[c], st1, 0, 0, 0);
    }
    __builtin_amdgcn_s_setprio(0);

    float t16[16];
#pragma unroll
    for (int r = 0; r < 16; ++r) t16[r] = fmaxf(st0[r], st1[r]);
#pragma unroll
    for (int off = 8; off > 0; off >>= 1)
#pragma unroll
      for (int i = 0; i < off; ++i) t16[i] = fmaxf(t16[i], t16[i + off]);
    float pmax = fmaxf(t16[0], __shfl_xor(t16[0], 32, 64));

    if (!__all(pmax - m <= 8.0f)) {
      float mn = fmaxf(m, pmax);
      float al = exp2f(m - mn);
      m = mn; l *= al;
#pragma unroll
      for (int r = 0; r < 16; ++r) { acc0[r] *= al; acc1[r] *= al; }
    }

#pragma unroll
    for (int r = 0; r < 16; ++r) {
      st0[r] = exp2f(st0[r] - m);
      st1[r] = exp2f(st1[r] - m);
    }
    float sm[16];
#pragma unroll
    for (int r = 0; r < 16; ++r) sm[r] = st0[r] + st1[r];
#pragma unroll
    for (int off = 8; off > 0; off >>= 1)
#pragma unroll
      for (int i = 0; i < off; ++i) sm[i] += sm[i + off];
    l += sm[0] + __shfl_xor(sm[0], 32, 64);

    bf16x8 pf[4];
#pragma unroll
    for (int s2 = 0; s2 < 2; ++s2) {
      W4 w0, w1;
#pragma unroll
      for (int i = 0; i < 4; ++i) {
        PK a, b;
        a.h[0] = (bf16_t)(s2 ? st1[2 * i]     : st0[2 * i]);
        a.h[1] = (bf16_t)(s2 ? st1[2 * i + 1] : st0[2 * i + 1]);
        b.h[0] = (bf16_t)(s2 ? st1[8 + 2 * i]     : st0[8 + 2 * i]);
        b.h[1] = (bf16_t)(s2 ? st1[8 + 2 * i + 1] : st0[8 + 2 * i + 1]);
        w0.u[i] = a.u; w1.u[i] = b.u;
      }
      pf[s2 * 2] = w0.v; pf[s2 * 2 + 1] = w1.v;
    }

    __builtin_amdgcn_s_setprio(1);
#pragma unroll
    for (int kc = 0; kc < 4; ++kc) {
      bf16x8 vf0 = *(const bf16x8*)&Vb[swz64(lq, kc * 16 + h * 8)];
      bf16x8 vf1 = *(const bf16x8*)&Vb[swz64(32 + lq, kc * 16 + h * 8)];
      acc0 = __builtin_amdgcn_mfma_f32_32x32x16_bf16(vf0, pf[kc], acc0, 0, 0, 0);
      acc1 = __builtin_amdgcn_mfma_f32_32x32x16_bf16(vf1, pf[kc], acc1, 0, 0, 0);
    }
    __builtin_amdgcn_s_setprio(0);

    if (kt + 1 < NKT) stage(cur ^ 1);
    __syncthreads();
  }

  float invl = 1.0f / l;
  float* op = O + base + (size_t)(q0 + lq) * D_DIM;
#pragma unroll
  for (int r = 0; r < 16; ++r) {
    int d = (r & 3) + 8 * (r >> 2) + 4 * h;
    op[d]      = acc0[r] * invl;
    op[32 + d] = acc1[r] * invl;
  }
}

extern "C" void kernel_launch(void* const* d_in, const int* in_sizes, int n_in,
                              void* d_out, int out_size, void* d_ws, size_t ws_size,
                              hipStream_t stream) {
  const float* q = (const float*)d_in[0];
  const float* k = (const float*)d_in[1];
  const float* v = (const float*)d_in[2];
  float* o = (float*)d_out;

  const size_t tile_cnt = (size_t)BH * NKT;               // 2048
  const size_t need = 2 * tile_cnt * TILE_ELEMS * sizeof(bf16_t);  // 33.5 MB

  if (ws_size >= need) {
    bf16_t* kws = (bf16_t*)d_ws;
    bf16_t* vws = kws + tile_cnt * TILE_ELEMS;
    preconv<<<(int)tile_cnt, 256, 0, stream>>>(k, v, kws, vws);
    sdpa_fwd_ws<<<NWG, 256, 0, stream>>>(q, kws, vws, o);
  } else {
    sdpa_fwd_fb<<<NWG, 256, 0, stream>>>(q, k, v, o);
  }
}

// Round 10
// 102.608 us; speedup vs baseline: 1.5846x; 1.5846x over previous
//
#include <hip/hip_runtime.h>
#include <hip/hip_bf16.h>

#define S_LEN 2048
#define D_DIM 64
#define BH 64
#define NWARP 4
#define QW 32                  // q rows per warp
#define QBLK (NWARP * QW)      // 128
#define KVBLK 64
#define NKT (S_LEN / KVBLK)    // 32
#define NWG (BH * S_LEN / QBLK)  // 1024
#define TILE_ELEMS (KVBLK * D_DIM)          // 4096 bf16 = 8KB
#define TILE_BYTES (TILE_ELEMS * 2)

typedef __bf16 bf16_t;
typedef bf16_t bf16x8 __attribute__((ext_vector_type(8)));
typedef float f32x4 __attribute__((ext_vector_type(4)));
typedef float f32x16 __attribute__((ext_vector_type(16)));

typedef const __attribute__((address_space(1))) void gvoid_t;
typedef __attribute__((address_space(3))) void lvoid_t;

// element-index swizzle for a 64-col bf16 tile (rows are 128B):
// byte ^= ((row&7)<<4)  ==  col ^= ((row&7)<<3)
__device__ __forceinline__ int swz64(int row, int col) {
  return (row << 6) + (col ^ ((row & 7) << 3));
}

union W4 { unsigned u[4]; bf16x8 v; };
union PK { bf16_t h[2]; unsigned u; };

// ---------------------------------------------------------------------------
// Pre-pass: K,V fp32 -> bf16 tiles in d_ws, stored as the exact swizzled LDS
// image (V transposed [d][pi(k)]), so the main kernel can DMA them linearly.
// ---------------------------------------------------------------------------
__global__ __launch_bounds__(256)
void preconv(const float* __restrict__ K, const float* __restrict__ V,
             bf16_t* __restrict__ Kws, bf16_t* __restrict__ Vws) {
  const int tile = blockIdx.x;            // bh*NKT + kt
  const int bh = tile >> 5, kt = tile & 31;
  const size_t base = (size_t)bh * S_LEN * D_DIM + (size_t)kt * KVBLK * D_DIM;
  const int tid = threadIdx.x;
  bf16_t* ko = Kws + (size_t)tile * TILE_ELEMS;
  bf16_t* vo = Vws + (size_t)tile * TILE_ELEMS;

  // K tile [64][64] fp32 -> bf16 swizzled
  const int krow = tid >> 2, kcb = tid & 3;
  const float* ks = K + base + (size_t)krow * D_DIM + kcb * 16;
  f32x4 kr[4];
#pragma unroll
  for (int i = 0; i < 4; ++i) kr[i] = *(const f32x4*)(ks + i * 4);
#pragma unroll
  for (int half = 0; half < 2; ++half) {
    bf16x8 f;
#pragma unroll
    for (int j = 0; j < 4; ++j) {
      f[j]     = (bf16_t)kr[half * 2][j];
      f[4 + j] = (bf16_t)kr[half * 2 + 1][j];
    }
    *(bf16x8*)&ko[swz64(krow, kcb * 16 + half * 8)] = f;
  }

  // V^T tile [d][pi(k)] packed pairs, swizzled
  const int vkp = tid & 31, vdb = tid >> 5;
  const int vk0 = vkp * 2;
  const int vcol = (((vk0 >> 2) ^ (vk0 >> 3)) & 1) ? (vk0 ^ 12) : vk0;
  const float* vs = V + base + (size_t)vk0 * D_DIM + vdb * 8;
  f32x4 vr[4];
  vr[0] = *(const f32x4*)vs;           vr[1] = *(const f32x4*)(vs + 4);
  vr[2] = *(const f32x4*)(vs + D_DIM); vr[3] = *(const f32x4*)(vs + D_DIM + 4);
#pragma unroll
  for (int j = 0; j < 8; ++j) {
    PK p;
    p.h[0] = (bf16_t)((j < 4) ? vr[0][j] : vr[1][j - 4]);
    p.h[1] = (bf16_t)((j < 4) ? vr[2][j] : vr[3][j - 4]);
    *(unsigned*)&vo[swz64(vdb * 8 + j, vcol)] = p.u;
  }
}

// ---------------------------------------------------------------------------
// Main kernel: DMA-staged flash attention with half-tile pipeline:
// epoch t = [barrier | issue(t+1) | qk_h0(t) | finish_h1(t-1) | qk_h1(t) |
//            finish_h0(t) | vmcnt(0)] -- finish VALU overlaps qk MFMA in-wave.
// K x2 buffers, V x3 buffers (40 KB). __launch_bounds__(256,3): cap 168 VGPR
// (peak live ~120; the (256,4)/128 cap spilled ~2KB/wave-epoch -> 298MB scratch
// writes, round 9 regression). 3 blocks/CU, no spills.
// ---------------------------------------------------------------------------
__global__ __launch_bounds__(256, 3)
void sdpa_fwd_ws(const float* __restrict__ Q, const bf16_t* __restrict__ Kws,
                 const bf16_t* __restrict__ Vws, float* __restrict__ O) {
  __shared__ bf16_t Klds[2][TILE_ELEMS];
  __shared__ bf16_t Vlds[3][TILE_ELEMS];

  // XCD-aware bijective swizzle (1024 = 8*128)
  const int bid = blockIdx.x;
  const int lb  = (bid & 7) * (NWG / 8) + (bid >> 3);
  const int bx  = lb & 15;
  const int bh  = lb >> 4;

  const int tid  = threadIdx.x;
  const int wave = tid >> 6;
  const int lane = tid & 63;
  const int lq   = lane & 31;
  const int h    = lane >> 5;

  const size_t base = (size_t)bh * S_LEN * D_DIM;
  const int q0 = bx * QBLK + wave * QW;
  const float qscale = 0.125f * 1.44269504089f;  // 1/sqrt(64) * log2(e)

  // Q B-operand fragments (log2-scaled): lane holds Q[q0+lq][c*16 + h*8 + j]
  bf16x8 qf[4];
  {
    const float* qp = Q + base + (size_t)(q0 + lq) * D_DIM + h * 8;
#pragma unroll
    for (int c = 0; c < 4; ++c) {
      f32x4 a = *(const f32x4*)(qp + c * 16);
      f32x4 b = *(const f32x4*)(qp + c * 16 + 4);
      bf16x8 f;
#pragma unroll
      for (int j = 0; j < 4; ++j) {
        f[j]     = (bf16_t)(a[j] * qscale);
        f[4 + j] = (bf16_t)(b[j] * qscale);
      }
      qf[c] = f;
    }
  }

  // DMA source (per-lane) and LDS dest (wave-uniform) bases
  const char* kg = (const char*)(Kws + (size_t)(bh * NKT) * TILE_ELEMS)
                   + wave * 2048 + lane * 16;
  const char* vg = (const char*)(Vws + (size_t)(bh * NKT) * TILE_ELEMS)
                   + wave * 2048 + lane * 16;

  auto issueK = [&](int kt, int buf) {
    const char* src = kg + (size_t)kt * TILE_BYTES;
    char* dst = (char*)&Klds[buf][0] + wave * 2048;
    __builtin_amdgcn_global_load_lds((gvoid_t*)src,          (lvoid_t*)dst,          16, 0, 0);
    __builtin_amdgcn_global_load_lds((gvoid_t*)(src + 1024), (lvoid_t*)(dst + 1024), 16, 0, 0);
  };
  auto issueV = [&](int kt, int buf) {
    const char* src = vg + (size_t)kt * TILE_BYTES;
    char* dst = (char*)&Vlds[0][0] + buf * TILE_BYTES + wave * 2048;
    __builtin_amdgcn_global_load_lds((gvoid_t*)src,          (lvoid_t*)dst,          16, 0, 0);
    __builtin_amdgcn_global_load_lds((gvoid_t*)(src + 1024), (lvoid_t*)(dst + 1024), 16, 0, 0);
  };

  f32x16 acc0 = {}, acc1 = {};   // O^T: col q=lq, rows d=(r&3)+8*(r>>2)+4h (+32 acc1)
  float lpart = 0.f;             // lane-local l partial; cross-half shfl at end

  // half-tile QK: role 0 -> K rows lq (k 0..31), role 1 -> rows 32+lq (k 32..63)
  auto qkh = [&](const bf16_t* Kb, int role) {
    f32x16 s = {};
    __builtin_amdgcn_s_setprio(1);
#pragma unroll
    for (int c = 0; c < 4; ++c) {
      bf16x8 kf = *(const bf16x8*)&Kb[swz64(role * 32 + lq, c * 16 + h * 8)];
      s = __builtin_amdgcn_mfma_f32_32x32x16_bf16(kf, qf[c], s, 0, 0, 0);
    }
    __builtin_amdgcn_s_setprio(0);
    return s;
  };

  // half-tile finish: exp -> lpart -> pack -> PV (kc = role*2 + {0,1})
  auto finh = [&](const bf16_t* Vb, int role, f32x16 s) {
#pragma unroll
    for (int r = 0; r < 16; ++r) s[r] = __builtin_amdgcn_exp2f(s[r]);
    float a0 = (s[0] + s[1]) + (s[2] + s[3]);
    float a1 = (s[4] + s[5]) + (s[6] + s[7]);
    float a2 = (s[8] + s[9]) + (s[10] + s[11]);
    float a3 = (s[12] + s[13]) + (s[14] + s[15]);
    lpart += (a0 + a1) + (a2 + a3);
    W4 w0, w1;
#pragma unroll
    for (int i = 0; i < 4; ++i) {
      PK a, b;
      a.h[0] = (bf16_t)s[2 * i];     a.h[1] = (bf16_t)s[2 * i + 1];
      b.h[0] = (bf16_t)s[8 + 2 * i]; b.h[1] = (bf16_t)s[8 + 2 * i + 1];
      w0.u[i] = a.u; w1.u[i] = b.u;
    }
    __builtin_amdgcn_s_setprio(1);
#pragma unroll
    for (int j = 0; j < 2; ++j) {
      const int kc = role * 2 + j;
      bf16x8 vf0 = *(const bf16x8*)&Vb[swz64(lq,      kc * 16 + h * 8)];
      bf16x8 vf1 = *(const bf16x8*)&Vb[swz64(32 + lq, kc * 16 + h * 8)];
      bf16x8 pf = j ? w1.v : w0.v;
      acc0 = __builtin_amdgcn_mfma_f32_32x32x16_bf16(vf0, pf, acc0, 0, 0, 0);
      acc1 = __builtin_amdgcn_mfma_f32_32x32x16_bf16(vf1, pf, acc1, 0, 0, 0);
    }
    __builtin_amdgcn_s_setprio(0);
  };

  f32x16 stA, stB, stP;

  // ---- prologue: tile 0
  issueK(0, 0); issueV(0, 0);
  asm volatile("s_waitcnt vmcnt(0)" ::: "memory");
  __builtin_amdgcn_s_barrier();
  __builtin_amdgcn_sched_barrier(0);
  issueK(1, 1); issueV(1, 1);
  stA = qkh(Klds[0], 0);
  stB = qkh(Klds[0], 1);
  finh(&Vlds[0][0], 0, stA);
  stP = stB;
  asm volatile("s_waitcnt vmcnt(0)" ::: "memory");

  int vbp = 0, vbc = 1, vbn = 2;   // V buffers for t-1, t, t+1

#pragma unroll 1
  for (int t = 1; t < NKT; ++t) {
    __builtin_amdgcn_s_barrier();            // tile t fully landed (all waves)
    __builtin_amdgcn_sched_barrier(0);
    if (t + 1 < NKT) { issueK(t + 1, (t + 1) & 1); issueV(t + 1, vbn); }

    const bf16_t* Kb = Klds[t & 1];
    const bf16_t* Vp = &Vlds[0][0] + vbp * TILE_ELEMS;
    const bf16_t* Vc = &Vlds[0][0] + vbc * TILE_ELEMS;

    stA = qkh(Kb, 0);        // MFMA: overlaps with ...
    finh(Vp, 1, stP);        // ... VALU finish of tile t-1 hi-half
    stB = qkh(Kb, 1);
    finh(Vc, 0, stA);        // finish tile t lo-half
    stP = stB;               // hi-half deferred to next epoch

    asm volatile("s_waitcnt vmcnt(0)" ::: "memory");  // t+1 landed (mine)

    int tmp = vbp; vbp = vbc; vbc = vbn; vbn = tmp;
  }
  // final deferred hi-half of tile NKT-1
  finh(&Vlds[0][0] + vbp * TILE_ELEMS, 1, stP);

  // ---- epilogue: O[q][d] = O^T / l
  float l = lpart + __shfl_xor(lpart, 32, 64);
  float invl = 1.0f / l;
  float* op = O + base + (size_t)(q0 + lq) * D_DIM;
#pragma unroll
  for (int r = 0; r < 16; ++r) {
    int d = (r & 3) + 8 * (r >> 2) + 4 * h;
    op[d]      = acc0[r] * invl;
    op[32 + d] = acc1[r] * invl;
  }
}

// ---------------------------------------------------------------------------
// Fallback (known-good round-4 kernel, no workspace) if ws_size too small.
// ---------------------------------------------------------------------------
__global__ __launch_bounds__(256, 2)
void sdpa_fwd_fb(const float* __restrict__ Q, const float* __restrict__ K,
                 const float* __restrict__ V, float* __restrict__ O) {
  __shared__ bf16_t Klds[2][KVBLK * D_DIM];
  __shared__ bf16_t VTlds[2][D_DIM * KVBLK];

  const int bid = blockIdx.x;
  const int lb  = (bid & 7) * (NWG / 8) + (bid >> 3);
  const int bx  = lb & 15;
  const int bh  = lb >> 4;

  const int tid  = threadIdx.x;
  const int wave = tid >> 6;
  const int lane = tid & 63;
  const int lq   = lane & 31;
  const int h    = lane >> 5;

  const size_t base = (size_t)bh * S_LEN * D_DIM;
  const int q0 = bx * QBLK + wave * QW;
  const float qscale = 0.125f * 1.44269504089f;

  bf16x8 qf[4];
  {
    const float* qp = Q + base + (size_t)(q0 + lq) * D_DIM + h * 8;
#pragma unroll
    for (int c = 0; c < 4; ++c) {
      f32x4 a = *(const f32x4*)(qp + c * 16);
      f32x4 b = *(const f32x4*)(qp + c * 16 + 4);
      bf16x8 f;
#pragma unroll
      for (int j = 0; j < 4; ++j) {
        f[j]     = (bf16_t)(a[j] * qscale);
        f[4 + j] = (bf16_t)(b[j] * qscale);
      }
      qf[c] = f;
    }
  }

  const int krow = tid >> 2, kcb = tid & 3;
  const int vkp = tid & 31, vdb = tid >> 5;
  const int vk0 = vkp * 2;
  const int vcol = (((vk0 >> 2) ^ (vk0 >> 3)) & 1) ? (vk0 ^ 12) : vk0;

  f32x4 kr[4], vr[4];

  auto issue = [&](int kt) {
    const float* ks = K + base + (size_t)(kt * KVBLK + krow) * D_DIM + kcb * 16;
#pragma unroll
    for (int i = 0; i < 4; ++i) kr[i] = *(const f32x4*)(ks + i * 4);
    const float* vs = V + base + (size_t)(kt * KVBLK + vk0) * D_DIM + vdb * 8;
    vr[0] = *(const f32x4*)vs;           vr[1] = *(const f32x4*)(vs + 4);
    vr[2] = *(const f32x4*)(vs + D_DIM); vr[3] = *(const f32x4*)(vs + D_DIM + 4);
  };

  auto stage = [&](int buf) {
#pragma unroll
    for (int half = 0; half < 2; ++half) {
      bf16x8 f;
#pragma unroll
      for (int j = 0; j < 4; ++j) {
        f[j]     = (bf16_t)kr[half * 2][j];
        f[4 + j] = (bf16_t)kr[half * 2 + 1][j];
      }
      *(bf16x8*)&Klds[buf][swz64(krow, kcb * 16 + half * 8)] = f;
    }
#pragma unroll
    for (int j = 0; j < 8; ++j) {
      PK p;
      p.h[0] = (bf16_t)((j < 4) ? vr[0][j] : vr[1][j - 4]);
      p.h[1] = (bf16_t)((j < 4) ? vr[2][j] : vr[3][j - 4]);
      *(unsigned*)&VTlds[buf][swz64(vdb * 8 + j, vcol)] = p.u;
    }
  };

  f32x16 acc0 = {}, acc1 = {};
  float m = -1e30f, l = 0.f;

  issue(0);
  stage(0);
  __syncthreads();

  for (int kt = 0; kt < NKT; ++kt) {
    const int cur = kt & 1;
    if (kt + 1 < NKT) issue(kt + 1);

    const bf16_t* Kb = Klds[cur];
    const bf16_t* Vb = VTlds[cur];

    f32x16 st0 = {}, st1 = {};
    __builtin_amdgcn_s_setprio(1);
#pragma unroll
    for (int c = 0; c < 4; ++c) {
      bf16x8 kf0 = *(const bf16x8*)&Kb[swz64(lq, c * 16 + h * 8)];
      bf16x8 kf1 = *(const bf16x8*)&Kb[swz64(32 + lq, c * 16 + h * 8)];
      st0 = __builtin_amdgcn_mfma_f32_32x32x16_bf16(kf0, qf[c], st0, 0, 0, 0);
      st1 = __builtin_amdgcn_mfma_f32_32x32x16_bf16(kf1, qf[c], st1, 0, 0, 0);
    }
    __builtin_amdgcn_s_setprio(0);

    float t16[16];
#pragma unroll
    for (int r = 0; r < 16; ++r) t16[r] = fmaxf(st0[r], st1[r]);
#pragma unroll
    for (int off = 8; off > 0; off >>= 1)
#pragma unroll
      for (int i = 0; i < off; ++i) t16[i] = fmaxf(t16[i], t16[i + off]);
    float pmax = fmaxf(t16[0], __shfl_xor(t16[0], 32, 64));

    if (!__all(pmax - m <= 8.0f)) {
      float mn = fmaxf(m, pmax);
      float al = exp2f(m - mn);
      m = mn; l *= al;
#pragma unroll
      for (int r = 0; r < 16; ++r) { acc0[r] *= al; acc1[r] *= al; }
    }

#pragma unroll
    for (int r = 0; r < 16; ++r) {
      st0[r] = exp2f(st0[r] - m);
      st1[r] = exp2f(st1[r] - m);
    }
    float sm[16];
#pragma unroll
    for (int r = 0; r < 16; ++r) sm[r] = st0[r] + st1[r];
#pragma unroll
    for (int off = 8; off > 0; off >>= 1)
#pragma unroll
      for (int i = 0; i < off; ++i) sm[i] += sm[i + off];
    l += sm[0] + __shfl_xor(sm[0], 32, 64);

    bf16x8 pf[4];
#pragma unroll
    for (int s2 = 0; s2 < 2; ++s2) {
      W4 w0, w1;
#pragma unroll
      for (int i = 0; i < 4; ++i) {
        PK a, b;
        a.h[0] = (bf16_t)(s2 ? st1[2 * i]     : st0[2 * i]);
        a.h[1] = (bf16_t)(s2 ? st1[2 * i + 1] : st0[2 * i + 1]);
        b.h[0] = (bf16_t)(s2 ? st1[8 + 2 * i]     : st0[8 + 2 * i]);
        b.h[1] = (bf16_t)(s2 ? st1[8 + 2 * i + 1] : st0[8 + 2 * i + 1]);
        w0.u[i] = a.u; w1.u[i] = b.u;
      }
      pf[s2 * 2] = w0.v; pf[s2 * 2 + 1] = w1.v;
    }

    __builtin_amdgcn_s_setprio(1);
#pragma unroll
    for (int kc = 0; kc < 4; ++kc) {
      bf16x8 vf0 = *(const bf16x8*)&Vb[swz64(lq, kc * 16 + h * 8)];
      bf16x8 vf1 = *(const bf16x8*)&Vb[swz64(32 + lq, kc * 16 + h * 8)];
      acc0 = __builtin_amdgcn_mfma_f32_32x32x16_bf16(vf0, pf[kc], acc0, 0, 0, 0);
      acc1 = __builtin_amdgcn_mfma_f32_32x32x16_bf16(vf1, pf[kc], acc1, 0, 0, 0);
    }
    __builtin_amdgcn_s_setprio(0);

    if (kt + 1 < NKT) stage(cur ^ 1);
    __syncthreads();
  }

  float invl = 1.0f / l;
  float* op = O + base + (size_t)(q0 + lq) * D_DIM;
#pragma unroll
  for (int r = 0; r < 16; ++r) {
    int d = (r & 3) + 8 * (r >> 2) + 4 * h;
    op[d]      = acc0[r] * invl;
    op[32 + d] = acc1[r] * invl;
  }
}

extern "C" void kernel_launch(void* const* d_in, const int* in_sizes, int n_in,
                              void* d_out, int out_size, void* d_ws, size_t ws_size,
                              hipStream_t stream) {
  const float* q = (const float*)d_in[0];
  const float* k = (const float*)d_in[1];
  const float* v = (const float*)d_in[2];
  float* o = (float*)d_out;

  const size_t tile_cnt = (size_t)BH * NKT;               // 2048
  const size_t need = 2 * tile_cnt * TILE_ELEMS * sizeof(bf16_t);  // 33.5 MB

  if (ws_size >= need) {
    bf16_t* kws = (bf16_t*)d_ws;
    bf16_t* vws = kws + tile_cnt * TILE_ELEMS;
    preconv<<<(int)tile_cnt, 256, 0, stream>>>(k, v, kws, vws);
    sdpa_fwd_ws<<<NWG, 256, 0, stream>>>(q, kws, vws, o);
  } else {
    sdpa_fwd_fb<<<NWG, 256, 0, stream>>>(q, k, v, o);
  }
}